// Round 1
// baseline (2591.140 us; speedup 1.0000x reference)
//
#include <hip/hip_runtime.h>
#include <math.h>

namespace {
constexpr int N_ = 8192;
constexpr int M_ = 16384;
constexpr int D_ = 512;
constexpr int K_ = 10;
constexpr float EPS_ = 1e-8f;

constexpr int BM = 32;
constexpr int BN = 128;
constexpr int BK = 32;
constexpr int MSPLIT = 8;
constexpr int MCHUNK = M_ / MSPLIT;   // 2048
constexpr int NTILES = MCHUNK / BN;   // 16
constexpr int KCH = D_ / BK;          // 16

constexpr int AS_STRIDE = BM + 4;     // 36 (keeps float4 LDS reads 16B-aligned, breaks bank aliasing)
constexpr int BS_STRIDE = BN + 4;     // 132
constexpr int SM_FLOATS = BK * AS_STRIDE + BK * BS_STRIDE;  // 1152 + 4224 = 5376 floats = 21.5 KB
}

__device__ __forceinline__ float wredsum(float v) {
#pragma unroll
  for (int o = 32; o > 0; o >>= 1) v += __shfl_xor(v, o);
  return v;
}
__device__ __forceinline__ float wredmin(float v) {
#pragma unroll
  for (int o = 32; o > 0; o >>= 1) v = fminf(v, __shfl_xor(v, o));
  return v;
}
__device__ __forceinline__ float wredmax(float v) {
#pragma unroll
  for (int o = 32; o > 0; o >>= 1) v = fmaxf(v, __shfl_xor(v, o));
  return v;
}

// ---------------- kernel 1: row norms for features (x2) and memory bank (m2) ----------------
__global__ __launch_bounds__(256) void rownorms_k(const float* __restrict__ feat,
                                                  const float* __restrict__ mem,
                                                  float* __restrict__ x2,
                                                  float* __restrict__ m2) {
  const int wv = threadIdx.x >> 6, lane = threadIdx.x & 63;
  const int w = blockIdx.x * 4 + wv;
  const float* src;
  float* dst;
  if (w < M_) {
    src = mem + (size_t)w * D_;
    dst = m2 + w;
  } else {
    const int r = w - M_;
    src = feat + (size_t)r * D_;
    dst = x2 + r;
  }
  const float4 a = *(const float4*)(src + lane * 4);
  const float4 b = *(const float4*)(src + 256 + lane * 4);
  float s = a.x * a.x + a.y * a.y + a.z * a.z + a.w * a.w +
            b.x * b.x + b.y * b.y + b.z * b.z + b.w * b.w;
  s = wredsum(s);
  if (lane == 0) *dst = s;
}

// ---------------- kernel 2: init global min/max (uint bit-pattern trick, values > 0) ----------------
__global__ void init_k(unsigned int* __restrict__ dmm) {
  if (threadIdx.x == 0) {
    dmm[0] = 0x7f7fffffu;  // FLT_MAX bits (running min)
    dmm[1] = 0u;           // running max
  }
}

#define TOPK_INSERT(LIST, LIDX, VAL, IDX)                         \
  do {                                                            \
    if ((VAL) < LIST[K_ - 1]) {                                   \
      int p_ = K_ - 1;                                            \
      while (p_ > 0 && (VAL) < LIST[p_ - 1]) {                    \
        LIST[p_] = LIST[p_ - 1];                                  \
        LIDX[p_] = LIDX[p_ - 1];                                  \
        --p_;                                                     \
      }                                                           \
      LIST[p_] = (VAL);                                           \
      LIDX[p_] = (IDX);                                           \
    }                                                             \
  } while (0)

// ---------------- kernel 3: fused distance GEMM + per-row partial top-10 ----------------
// grid (N/BM=256, MSPLIT=8), block 256. Each block: 32 rows x 2048 cols.
__global__ __launch_bounds__(256) void knn_partial_k(
    const float* __restrict__ A, const float* __restrict__ B,
    const float* __restrict__ x2, const float* __restrict__ m2,
    float* __restrict__ pdist, int* __restrict__ pidx) {
  __shared__ float sm[SM_FLOATS];
  float* As = sm;                    // [BK][AS_STRIDE], transposed A chunk
  float* Bs = sm + BK * AS_STRIDE;   // [BK][BS_STRIDE], transposed B chunk; reused as dist tile [BM][BS_STRIDE]

  const int tid = threadIdx.x;
  const int row0 = blockIdx.x * BM;
  const int colBase = blockIdx.y * MCHUNK;

  const int rg = tid >> 5, cg = tid & 31;
  const int r0 = rg * 4, c0 = cg * 4;

  float x2r[4];
#pragma unroll
  for (int i = 0; i < 4; i++) x2r[i] = x2[row0 + r0 + i];

  float list[K_];
  int lidx[K_];
#pragma unroll
  for (int i = 0; i < K_; i++) {
    list[i] = 3.4e38f;
    lidx[i] = 0;
  }
  const int srow = tid >> 3, spart = tid & 7;  // top-K scan: 8 threads per row

  const int lar = tid >> 3;         // staging row/col 0..31
  const int lak = (tid & 7) * 4;    // staging k offset

  for (int t = 0; t < NTILES; ++t) {
    const int col0 = colBase + t * BN;
    float acc[4][4] = {{0.f}};
    for (int kc = 0; kc < KCH; ++kc) {
      const int k0 = kc * BK;
      __syncthreads();  // protect As/Bs vs previous readers (kk loop / dist scan)
      {
        const float4 av = *(const float4*)(A + (size_t)(row0 + lar) * D_ + k0 + lak);
        As[(lak + 0) * AS_STRIDE + lar] = av.x;
        As[(lak + 1) * AS_STRIDE + lar] = av.y;
        As[(lak + 2) * AS_STRIDE + lar] = av.z;
        As[(lak + 3) * AS_STRIDE + lar] = av.w;
      }
#pragma unroll
      for (int q = 0; q < 4; q++) {
        const int bc = lar + 32 * q;
        const float4 bv = *(const float4*)(B + (size_t)(col0 + bc) * D_ + k0 + lak);
        Bs[(lak + 0) * BS_STRIDE + bc] = bv.x;
        Bs[(lak + 1) * BS_STRIDE + bc] = bv.y;
        Bs[(lak + 2) * BS_STRIDE + bc] = bv.z;
        Bs[(lak + 3) * BS_STRIDE + bc] = bv.w;
      }
      __syncthreads();
#pragma unroll
      for (int kk = 0; kk < BK; ++kk) {
        const float4 a4 = *(const float4*)(As + kk * AS_STRIDE + r0);
        const float4 b4 = *(const float4*)(Bs + kk * BS_STRIDE + c0);
        const float av[4] = {a4.x, a4.y, a4.z, a4.w};
        const float bv[4] = {b4.x, b4.y, b4.z, b4.w};
#pragma unroll
        for (int i = 0; i < 4; i++)
#pragma unroll
          for (int j = 0; j < 4; j++) acc[i][j] = fmaf(av[i], bv[j], acc[i][j]);
      }
    }
    __syncthreads();  // all compute reads of Bs done; reuse Bs as dist tile
    const float4 m4 = *(const float4*)(m2 + col0 + c0);
    const float m2v[4] = {m4.x, m4.y, m4.z, m4.w};
#pragma unroll
    for (int i = 0; i < 4; i++) {
      float4 dv;
      float* dp = &dv.x;
#pragma unroll
      for (int j = 0; j < 4; j++) {
        const float dsq = x2r[i] + m2v[j] - 2.0f * acc[i][j];
        dp[j] = sqrtf(fmaxf(dsq, 0.0f) + EPS_);
      }
      *(float4*)(Bs + (size_t)(r0 + i) * BS_STRIDE + c0) = dv;
    }
    __syncthreads();
    // scan: thread (srow, spart) scans 16 contiguous cols of its row, ascending index
#pragma unroll
    for (int q = 0; q < 4; q++) {
      const float4 dv = *(const float4*)(Bs + (size_t)srow * BS_STRIDE + spart * 16 + q * 4);
      const float dvv[4] = {dv.x, dv.y, dv.z, dv.w};
#pragma unroll
      for (int e = 0; e < 4; e++) {
        const float v = dvv[e];
        const int gidx = col0 + spart * 16 + q * 4 + e;
        TOPK_INSERT(list, lidx, v, gidx);
      }
    }
  }
  // merge 8 partial lists per row inside the block
  __syncthreads();
  float* md = sm;                 // 32*80 = 2560 floats
  int* mi = (int*)(sm + 2560);    // 2560 ints (fits: 5376 words total)
#pragma unroll
  for (int k = 0; k < K_; k++) {
    md[srow * 80 + spart * K_ + k] = list[k];
    mi[srow * 80 + spart * K_ + k] = lidx[k];
  }
  __syncthreads();
  if (tid < BM) {
    const int row = tid;
    float fl[K_];
    int fi[K_];
#pragma unroll
    for (int i = 0; i < K_; i++) {
      fl[i] = 3.4e38f;
      fi[i] = 0;
    }
    for (int p = 0; p < 8 * K_; p++) {
      const float v = md[row * 80 + p];
      const int ix = mi[row * 80 + p];
      TOPK_INSERT(fl, fi, v, ix);
    }
    const size_t base = ((size_t)(row0 + row) * MSPLIT + blockIdx.y) * K_;
#pragma unroll
    for (int k = 0; k < K_; k++) {
      pdist[base + k] = fl[k];
      pidx[base + k] = fi[k];
    }
  }
}

// ---------------- kernel 4: merge MSPLIT partials per row, write knn distances, ds, global min/max ----------------
__global__ __launch_bounds__(256) void merge_k(
    const float* __restrict__ pdist, const int* __restrict__ pidx,
    float* __restrict__ knn_out, int* __restrict__ nn1, float* __restrict__ ds,
    unsigned int* __restrict__ dmm) {
  const int row = blockIdx.x * 256 + threadIdx.x;
  float fl[K_];
  int fi[K_];
#pragma unroll
  for (int i = 0; i < K_; i++) {
    fl[i] = 3.4e38f;
    fi[i] = 0;
  }
  const size_t base = (size_t)row * MSPLIT * K_;
  for (int p = 0; p < MSPLIT * K_; p++) {
    const float v = pdist[base + p];
    const int ix = pidx[base + p];
    TOPK_INSERT(fl, fi, v, ix);
  }
  float s = 0.f;
#pragma unroll
  for (int k = 0; k < K_; k++) {
    knn_out[(size_t)row * K_ + k] = fl[k];
    s += fl[k];
  }
  nn1[row] = fi[0];
  const float m = s * (1.0f / K_);
  ds[row] = m;
  float mn = m, mx = m;
#pragma unroll
  for (int o = 32; o > 0; o >>= 1) {
    mn = fminf(mn, __shfl_xor(mn, o));
    mx = fmaxf(mx, __shfl_xor(mx, o));
  }
  if ((threadIdx.x & 63) == 0) {
    atomicMin(&dmm[0], __float_as_uint(mn));  // all values > 0: uint order == float order
    atomicMax(&dmm[1], __float_as_uint(mx));
  }
}

// ---------------- kernel 5: influence + noise_std ----------------
__global__ __launch_bounds__(256) void finalize_k(
    const float* __restrict__ feat, const float* __restrict__ mem,
    const float* __restrict__ knn, const int* __restrict__ nn1,
    const float* __restrict__ ds, const unsigned int* __restrict__ dmm,
    const float* __restrict__ iscale, const float* __restrict__ dscale,
    float* __restrict__ out_infl, float* __restrict__ out_noise) {
  const int wv = threadIdx.x >> 6, lane = threadIdx.x & 63;
  const int row = blockIdx.x * 4 + wv;
  const float d0 = knn[(size_t)row * K_];
  const float norm = d0 + EPS_;
  const int nb = nn1[row];
  const float dmin = __uint_as_float(dmm[0]);
  const float dmax = __uint_as_float(dmm[1]);
  const float dnorm = (ds[row] - dmin) / (dmax - dmin + EPS_);
  const float is = iscale[0], dsc = dscale[0];
  const size_t fb = (size_t)row * D_;
  const size_t nbase = (size_t)nb * D_;
  const float4 f0 = *(const float4*)(feat + fb + lane * 4);
  const float4 f1 = *(const float4*)(feat + fb + 256 + lane * 4);
  const float4 n0 = *(const float4*)(mem + nbase + lane * 4);
  const float4 n1 = *(const float4*)(mem + nbase + 256 + lane * 4);
  const float rn = 1.0f / norm;
  float inf[8];
  inf[0] = fabsf(f0.x - n0.x) * rn;
  inf[1] = fabsf(f0.y - n0.y) * rn;
  inf[2] = fabsf(f0.z - n0.z) * rn;
  inf[3] = fabsf(f0.w - n0.w) * rn;
  inf[4] = fabsf(f1.x - n1.x) * rn;
  inf[5] = fabsf(f1.y - n1.y) * rn;
  inf[6] = fabsf(f1.z - n1.z) * rn;
  inf[7] = fabsf(f1.w - n1.w) * rn;
  float mn = inf[0], mx = inf[0];
#pragma unroll
  for (int e = 1; e < 8; e++) {
    mn = fminf(mn, inf[e]);
    mx = fmaxf(mx, inf[e]);
  }
  mn = wredmin(mn);
  mx = wredmax(mx);
  const float inv = 1.0f / (mx - mn + EPS_);
  const float bd = dsc * dnorm;
  float nz[8];
#pragma unroll
  for (int e = 0; e < 8; e++) {
    const float innorm = (inf[e] - mn) * inv;
    const float comb = is * innorm + bd;
    nz[e] = 0.01f + 0.49f / (1.0f + expf(0.5f - comb));  // sigmoid(comb - 0.5)
  }
  *(float4*)(out_infl + fb + lane * 4) = make_float4(inf[0], inf[1], inf[2], inf[3]);
  *(float4*)(out_infl + fb + 256 + lane * 4) = make_float4(inf[4], inf[5], inf[6], inf[7]);
  *(float4*)(out_noise + fb + lane * 4) = make_float4(nz[0], nz[1], nz[2], nz[3]);
  *(float4*)(out_noise + fb + 256 + lane * 4) = make_float4(nz[4], nz[5], nz[6], nz[7]);
}

extern "C" void kernel_launch(void* const* d_in, const int* in_sizes, int n_in,
                              void* d_out, int out_size, void* d_ws, size_t ws_size,
                              hipStream_t stream) {
  const float* feat = (const float*)d_in[0];
  const float* mem = (const float*)d_in[1];
  const float* isc = (const float*)d_in[2];
  const float* dsc = (const float*)d_in[3];
  float* out = (float*)d_out;
  float* out_infl = out;
  float* out_noise = out + (size_t)N_ * D_;
  float* out_knn = out + (size_t)2 * N_ * D_;

  char* ws = (char*)d_ws;
  float* m2 = (float*)(ws);                                   // 16384 f
  float* x2 = (float*)(ws + 65536);                           // 8192 f
  float* ds = (float*)(ws + 98304);                           // 8192 f
  unsigned int* dmm = (unsigned int*)(ws + 131072);           // 2 u32
  int* nn1 = (int*)(ws + 131328);                             // 8192 i32
  float* pdist = (float*)(ws + 164864);                       // N*MSPLIT*K f = 2.62 MB
  int* pidx = (int*)(ws + 164864 + (size_t)N_ * MSPLIT * K_ * 4);  // 2.62 MB

  hipLaunchKernelGGL(rownorms_k, dim3((M_ + N_) / 4), dim3(256), 0, stream, feat, mem, x2, m2);
  hipLaunchKernelGGL(init_k, dim3(1), dim3(64), 0, stream, dmm);
  hipLaunchKernelGGL(knn_partial_k, dim3(N_ / BM, MSPLIT), dim3(256), 0, stream,
                     feat, mem, x2, m2, pdist, pidx);
  hipLaunchKernelGGL(merge_k, dim3(N_ / 256), dim3(256), 0, stream,
                     pdist, pidx, out_knn, nn1, ds, dmm);
  hipLaunchKernelGGL(finalize_k, dim3(N_ / 4), dim3(256), 0, stream,
                     feat, mem, out_knn, nn1, ds, dmm, isc, dsc, out_infl, out_noise);
}

// Round 2
// 1820.648 us; speedup vs baseline: 1.4232x; 1.4232x over previous
//
#include <hip/hip_runtime.h>
#include <hip/hip_bf16.h>
#include <math.h>

typedef __attribute__((ext_vector_type(8))) short bf16x8;
typedef __attribute__((ext_vector_type(8))) short short8v;
typedef __attribute__((ext_vector_type(4))) float f32x4;

namespace {
constexpr int N_ = 8192;
constexpr int M_ = 16384;
constexpr int D_ = 512;
constexpr int K_ = 10;
constexpr float EPS_ = 1e-8f;

constexpr int CAND = 16;            // candidates kept per row (rescored in fp32)
constexpr int CMSPLIT = 16;         // column chunks
constexpr int CCHUNK = M_ / CMSPLIT;   // 1024 cols per block
constexpr int CTILES = CCHUNK / 128;   // 8 col-tiles of 128
constexpr int KT = D_ / 64;            // 8 K-tiles of 64
constexpr int DSTR = 68;               // dist-tile LDS stride (f32), 16B-aligned rows, breaks bank alias
}

__device__ __forceinline__ float wredsum(float v) {
#pragma unroll
  for (int o = 32; o > 0; o >>= 1) v += __shfl_xor(v, o);
  return v;
}
__device__ __forceinline__ float wredmin(float v) {
#pragma unroll
  for (int o = 32; o > 0; o >>= 1) v = fminf(v, __shfl_xor(v, o));
  return v;
}
__device__ __forceinline__ float wredmax(float v) {
#pragma unroll
  for (int o = 32; o > 0; o >>= 1) v = fmaxf(v, __shfl_xor(v, o));
  return v;
}

// branchless sorted-ascending insert; all indices static (stays in VGPRs)
template <int KK>
__device__ __forceinline__ void ins_sorted(float (&L)[KK], int (&X)[KK], float v, int ix) {
  if (v >= L[KK - 1]) return;
#pragma unroll
  for (int j = KK - 1; j > 0; --j) {
    const bool sh = v < L[j - 1];
    const bool here = !sh && (v < L[j]);
    L[j] = sh ? L[j - 1] : (here ? v : L[j]);
    X[j] = sh ? X[j - 1] : (here ? ix : X[j]);
  }
  if (v < L[0]) { L[0] = v; X[0] = ix; }
}

__device__ __forceinline__ void gl_lds16(const void* g, void* l) {
  __builtin_amdgcn_global_load_lds(
      (const __attribute__((address_space(1))) unsigned int*)g,
      (__attribute__((address_space(3))) unsigned int*)l, 16, 0, 0);
}

__device__ __forceinline__ unsigned short f2bf(float v) {
  __hip_bfloat16 h = __float2bfloat16(v);
  return *reinterpret_cast<unsigned short*>(&h);
}

// ---------------- kernel 1: row norms + bf16 conversion (1 wave / row) ----------------
__global__ __launch_bounds__(256) void prep_k(const float* __restrict__ feat,
                                              const float* __restrict__ mem,
                                              float* __restrict__ x2, float* __restrict__ m2,
                                              unsigned short* __restrict__ fbf,
                                              unsigned short* __restrict__ mbf) {
  const int wv = threadIdx.x >> 6, lane = threadIdx.x & 63;
  const int w = blockIdx.x * 4 + wv;
  const float* src;
  float* dst;
  unsigned short* bdst;
  if (w < M_) {
    src = mem + (size_t)w * D_; dst = m2 + w; bdst = mbf + (size_t)w * D_;
  } else {
    const int r = w - M_;
    src = feat + (size_t)r * D_; dst = x2 + r; bdst = fbf + (size_t)r * D_;
  }
  const float4 a = *(const float4*)(src + lane * 8);
  const float4 b = *(const float4*)(src + lane * 8 + 4);
  float s = a.x * a.x + a.y * a.y + a.z * a.z + a.w * a.w +
            b.x * b.x + b.y * b.y + b.z * b.z + b.w * b.w;
  s = wredsum(s);
  if (lane == 0) *dst = s;
  short8v pk;
  pk[0] = (short)f2bf(a.x); pk[1] = (short)f2bf(a.y);
  pk[2] = (short)f2bf(a.z); pk[3] = (short)f2bf(a.w);
  pk[4] = (short)f2bf(b.x); pk[5] = (short)f2bf(b.y);
  pk[6] = (short)f2bf(b.z); pk[7] = (short)f2bf(b.w);
  *(short8v*)(bdst + lane * 8) = pk;
}

// ---------------- kernel 2: init global min/max ----------------
__global__ void init_k(unsigned int* __restrict__ dmm) {
  if (threadIdx.x == 0) {
    dmm[0] = 0x7f7fffffu;  // FLT_MAX bits (running min)
    dmm[1] = 0u;           // running max (all values > 0)
  }
}

// ---------------- kernel 3: bf16 MFMA candidate generation ----------------
// grid (N/128=64, CMSPLIT=16), block 256 (4 waves, 2x2 of 64x64 output each).
// Key = m2[c] - 2*cross (monotone in distance per row). Per-row top-16 per chunk.
__global__ __launch_bounds__(256) void candgen_k(
    const unsigned short* __restrict__ Abf, const unsigned short* __restrict__ Bbf,
    const float* __restrict__ m2,
    float* __restrict__ pdist, int* __restrict__ pidx) {
  __shared__ char smraw[DSTR * 128 * 4];  // 34816 B; staging(32KB) / dist / merge all overlap
  unsigned short* As = (unsigned short*)smraw;  // [128][64] bf16, linear (global_load_lds dest)
  unsigned short* Bs = As + 8192;               // [128][64]
  float* Ds = (float*)smraw;                    // [128][DSTR] dist keys (reuses dead staging)

  const int tid = threadIdx.x;
  const int wid = tid >> 6, lane = tid & 63;
  const int wr = wid >> 1, wc = wid & 1;
  const int lr = lane & 15, lg = lane >> 4;
  const int row0 = blockIdx.x * 128;
  const int chunk0 = blockIdx.y * CCHUNK;

  const int srow = tid >> 3;           // staging row 0..31 (per it)
  const int sbyte = (tid & 7) * 16;    // staging byte-in-row
  const char* Ag = (const char*)Abf + (size_t)(row0 + srow) * 1024 + sbyte;
  char* AsLds = smraw + wid * 1024;
  char* BsLds = smraw + 16384 + wid * 1024;

  float list[CAND];
  int lidx[CAND];
#pragma unroll
  for (int i = 0; i < CAND; i++) { list[i] = 3.4e38f; lidx[i] = 0; }
  const int sr = tid >> 1, sp = tid & 1;  // scan: 2 threads/row

  for (int t = 0; t < CTILES; ++t) {
    const int col0 = chunk0 + t * 128;
    f32x4 acc[4][4];
#pragma unroll
    for (int m = 0; m < 4; m++)
#pragma unroll
      for (int n = 0; n < 4; n++) acc[m][n] = (f32x4){0.f, 0.f, 0.f, 0.f};

    const char* Bg = (const char*)Bbf + (size_t)(col0 + srow) * 1024 + sbyte;
    for (int kt = 0; kt < KT; ++kt) {
      __syncthreads();  // previous LDS readers (MFMA frags / scan pass) done
#pragma unroll
      for (int it = 0; it < 4; ++it) {
        gl_lds16(Ag + kt * 128 + (size_t)it * 32768, AsLds + it * 4096);
        gl_lds16(Bg + kt * 128 + (size_t)it * 32768, BsLds + it * 4096);
      }
      __syncthreads();
#pragma unroll
      for (int kk = 0; kk < 2; ++kk) {
        bf16x8 af[4], bfg[4];
#pragma unroll
        for (int m = 0; m < 4; m++)
          af[m] = *(const bf16x8*)(As + (wr * 64 + m * 16 + lr) * 64 + kk * 32 + lg * 8);
#pragma unroll
        for (int n = 0; n < 4; n++)
          bfg[n] = *(const bf16x8*)(Bs + (wc * 64 + n * 16 + lr) * 64 + kk * 32 + lg * 8);
#pragma unroll
        for (int m = 0; m < 4; m++)
#pragma unroll
          for (int n = 0; n < 4; n++)
            acc[m][n] = __builtin_amdgcn_mfma_f32_16x16x32_bf16(af[m], bfg[n], acc[m][n], 0, 0, 0);
      }
    }
    // two 64-col passes: write keys into reused LDS, then scan
#pragma unroll
    for (int h = 0; h < 2; ++h) {
      __syncthreads();  // staging/scan LDS free
      if (wc == h) {    // wave-uniform branch: the 2 waves owning these 64 cols write
#pragma unroll
        for (int n = 0; n < 4; n++) {
          const float m2v = m2[col0 + wc * 64 + n * 16 + lr];
#pragma unroll
          for (int m = 0; m < 4; m++) {
#pragma unroll
            for (int j = 0; j < 4; j++) {
              const int row = wr * 64 + m * 16 + lg * 4 + j;  // C/D layout: row=(lane>>4)*4+reg
              Ds[row * DSTR + n * 16 + lr] = m2v - 2.0f * acc[m][n][j];
            }
          }
        }
      }
      __syncthreads();
      const int cb = col0 + h * 64 + sp * 32;
#pragma unroll
      for (int q = 0; q < 8; ++q) {
        const float4 v4 = *(const float4*)(Ds + sr * DSTR + sp * 32 + q * 4);
        const float vv[4] = {v4.x, v4.y, v4.z, v4.w};
#pragma unroll
        for (int e = 0; e < 4; ++e) ins_sorted<CAND>(list, lidx, vv[e], cb + q * 4 + e);
      }
    }
  }
  // block merge: 2 partial lists per row -> top-16 per row per chunk
  __syncthreads();
  float* Md = (float*)smraw;            // [128][2][16] f32
  int* Mi = (int*)smraw + 4096;         // [128][2][16] i32 (total 32KB <= 34816)
#pragma unroll
  for (int k = 0; k < CAND; k++) {
    Md[(sr * 2 + sp) * CAND + k] = list[k];
    Mi[(sr * 2 + sp) * CAND + k] = lidx[k];
  }
  __syncthreads();
  if (tid < 128) {
    float L[CAND];
    int X[CAND];
#pragma unroll
    for (int i = 0; i < CAND; i++) { L[i] = 3.4e38f; X[i] = 0; }
    for (int p = 0; p < 32; ++p) ins_sorted<CAND>(L, X, Md[tid * 32 + p], Mi[tid * 32 + p]);
    const size_t base = ((size_t)(row0 + tid) * CMSPLIT + blockIdx.y) * CAND;
#pragma unroll
    for (int k = 0; k < CAND; k++) { pdist[base + k] = L[k]; pidx[base + k] = X[k]; }
  }
}

// ---------------- kernel 4: merge chunk candidates -> top-16 per row ----------------
__global__ __launch_bounds__(256) void merge16_k(const float* __restrict__ pdist,
                                                 const int* __restrict__ pidx,
                                                 int* __restrict__ cidx) {
  const int row = blockIdx.x * 256 + threadIdx.x;
  float L[CAND];
  int X[CAND];
#pragma unroll
  for (int i = 0; i < CAND; i++) { L[i] = 3.4e38f; X[i] = 0; }
  const size_t base = (size_t)row * CMSPLIT * CAND;
  for (int p = 0; p < CMSPLIT * CAND; ++p) ins_sorted<CAND>(L, X, pdist[base + p], pidx[base + p]);
#pragma unroll
  for (int k = 0; k < CAND; k++) cidx[row * CAND + k] = X[k];
}

// ---------------- kernel 5: fp32 exact rescore of 16 candidates -> exact top-10 ----------------
__global__ __launch_bounds__(256) void rescore_k(
    const float* __restrict__ feat, const float* __restrict__ mem,
    const int* __restrict__ cidx, const float* __restrict__ x2, const float* __restrict__ m2,
    float* __restrict__ knn_out, int* __restrict__ nn1, float* __restrict__ dsArr,
    unsigned int* __restrict__ dmm) {
  __shared__ float rmn[4], rmx[4];
  const int wv = threadIdx.x >> 6, lane = threadIdx.x & 63;
  const int row = blockIdx.x * 4 + wv;
  const size_t fb = (size_t)row * D_;
  const float4 f0 = *(const float4*)(feat + fb + lane * 8);
  const float4 f1 = *(const float4*)(feat + fb + lane * 8 + 4);
  const float x2r = x2[row];
  float d16[CAND];
  int ci[CAND];
#pragma unroll
  for (int c = 0; c < CAND; ++c) {
    const int ix = cidx[row * CAND + c];
    ci[c] = ix;
    const size_t mb = (size_t)ix * D_;
    const float4 g0 = *(const float4*)(mem + mb + lane * 8);
    const float4 g1 = *(const float4*)(mem + mb + lane * 8 + 4);
    float s = f0.x * g0.x + f0.y * g0.y + f0.z * g0.z + f0.w * g0.w +
              f1.x * g1.x + f1.y * g1.y + f1.z * g1.z + f1.w * g1.w;
    s = wredsum(s);
    d16[c] = sqrtf(fmaxf(x2r + m2[ix] - 2.0f * s, 0.0f) + EPS_);
  }
  float L[K_];
  int X[K_];
#pragma unroll
  for (int i = 0; i < K_; i++) { L[i] = 3.4e38f; X[i] = 0; }
#pragma unroll
  for (int c = 0; c < CAND; ++c) ins_sorted<K_>(L, X, d16[c], ci[c]);
  float s10 = 0.f;
#pragma unroll
  for (int k = 0; k < K_; k++) s10 += L[k];
  const float mean = s10 * 0.1f;
  if (lane == 0) {
#pragma unroll
    for (int k = 0; k < K_; k++) knn_out[(size_t)row * K_ + k] = L[k];
    nn1[row] = X[0];
    dsArr[row] = mean;
    rmn[wv] = mean;
    rmx[wv] = mean;
  }
  __syncthreads();
  if (threadIdx.x == 0) {
    const float mn = fminf(fminf(rmn[0], rmn[1]), fminf(rmn[2], rmn[3]));
    const float mx = fmaxf(fmaxf(rmx[0], rmx[1]), fmaxf(rmx[2], rmx[3]));
    atomicMin(&dmm[0], __float_as_uint(mn));
    atomicMax(&dmm[1], __float_as_uint(mx));
  }
}

// ---------------- kernel 6: influence + noise_std ----------------
__global__ __launch_bounds__(256) void finalize_k(
    const float* __restrict__ feat, const float* __restrict__ mem,
    const float* __restrict__ knn, const int* __restrict__ nn1,
    const float* __restrict__ ds, const unsigned int* __restrict__ dmm,
    const float* __restrict__ iscale, const float* __restrict__ dscale,
    float* __restrict__ out_infl, float* __restrict__ out_noise) {
  const int wv = threadIdx.x >> 6, lane = threadIdx.x & 63;
  const int row = blockIdx.x * 4 + wv;
  const float d0 = knn[(size_t)row * K_];
  const float norm = d0 + EPS_;
  const int nb = nn1[row];
  const float dmin = __uint_as_float(dmm[0]);
  const float dmax = __uint_as_float(dmm[1]);
  const float dnorm = (ds[row] - dmin) / (dmax - dmin + EPS_);
  const float is = iscale[0], dsc = dscale[0];
  const size_t fb = (size_t)row * D_;
  const size_t nbase = (size_t)nb * D_;
  const float4 f0 = *(const float4*)(feat + fb + lane * 4);
  const float4 f1 = *(const float4*)(feat + fb + 256 + lane * 4);
  const float4 n0 = *(const float4*)(mem + nbase + lane * 4);
  const float4 n1 = *(const float4*)(mem + nbase + 256 + lane * 4);
  const float rn = 1.0f / norm;
  float inf[8];
  inf[0] = fabsf(f0.x - n0.x) * rn;
  inf[1] = fabsf(f0.y - n0.y) * rn;
  inf[2] = fabsf(f0.z - n0.z) * rn;
  inf[3] = fabsf(f0.w - n0.w) * rn;
  inf[4] = fabsf(f1.x - n1.x) * rn;
  inf[5] = fabsf(f1.y - n1.y) * rn;
  inf[6] = fabsf(f1.z - n1.z) * rn;
  inf[7] = fabsf(f1.w - n1.w) * rn;
  float mn = inf[0], mx = inf[0];
#pragma unroll
  for (int e = 1; e < 8; e++) {
    mn = fminf(mn, inf[e]);
    mx = fmaxf(mx, inf[e]);
  }
  mn = wredmin(mn);
  mx = wredmax(mx);
  const float inv = 1.0f / (mx - mn + EPS_);
  const float bd = dsc * dnorm;
  float nz[8];
#pragma unroll
  for (int e = 0; e < 8; e++) {
    const float innorm = (inf[e] - mn) * inv;
    const float comb = is * innorm + bd;
    nz[e] = 0.01f + 0.49f / (1.0f + expf(0.5f - comb));  // NOISE_MIN + range*sigmoid(comb-0.5)
  }
  *(float4*)(out_infl + fb + lane * 4) = make_float4(inf[0], inf[1], inf[2], inf[3]);
  *(float4*)(out_infl + fb + 256 + lane * 4) = make_float4(inf[4], inf[5], inf[6], inf[7]);
  *(float4*)(out_noise + fb + lane * 4) = make_float4(nz[0], nz[1], nz[2], nz[3]);
  *(float4*)(out_noise + fb + 256 + lane * 4) = make_float4(nz[4], nz[5], nz[6], nz[7]);
}

extern "C" void kernel_launch(void* const* d_in, const int* in_sizes, int n_in,
                              void* d_out, int out_size, void* d_ws, size_t ws_size,
                              hipStream_t stream) {
  const float* feat = (const float*)d_in[0];
  const float* mem = (const float*)d_in[1];
  const float* isc = (const float*)d_in[2];
  const float* dsc = (const float*)d_in[3];
  float* out = (float*)d_out;
  float* out_infl = out;
  float* out_noise = out + (size_t)N_ * D_;
  float* out_knn = out + (size_t)2 * N_ * D_;

  char* ws = (char*)d_ws;
  float* m2 = (float*)(ws + 0);                       //   64 KB
  float* x2 = (float*)(ws + 65536);                   //   32 KB
  float* dsA = (float*)(ws + 98304);                  //   32 KB
  unsigned int* dmm = (unsigned int*)(ws + 131072);   //   256 B
  int* nn1 = (int*)(ws + 131328);                     //   32 KB
  int* cidx = (int*)(ws + 164096);                    //  512 KB (N*16 i32)
  unsigned short* fbf = (unsigned short*)(ws + 688384);        // 8 MB (N*D bf16)
  unsigned short* mbf = (unsigned short*)(ws + 9076992);       // 16 MB (M*D bf16)
  float* pdist = (float*)(ws + 25854208);                      // 8 MB (N*16*16 f32)
  int* pidx = (int*)(ws + 34242816);                           // 8 MB

  hipLaunchKernelGGL(prep_k, dim3((M_ + N_) / 4), dim3(256), 0, stream, feat, mem, x2, m2, fbf, mbf);
  hipLaunchKernelGGL(init_k, dim3(1), dim3(64), 0, stream, dmm);
  hipLaunchKernelGGL(candgen_k, dim3(N_ / 128, CMSPLIT), dim3(256), 0, stream,
                     fbf, mbf, m2, pdist, pidx);
  hipLaunchKernelGGL(merge16_k, dim3(N_ / 256), dim3(256), 0, stream, pdist, pidx, cidx);
  hipLaunchKernelGGL(rescore_k, dim3(N_ / 4), dim3(256), 0, stream,
                     feat, mem, cidx, x2, m2, out_knn, nn1, dsA, dmm);
  hipLaunchKernelGGL(finalize_k, dim3(N_ / 4), dim3(256), 0, stream,
                     feat, mem, out_knn, nn1, dsA, dmm, isc, dsc, out_infl, out_noise);
}